// Round 1
// 252.239 us; speedup vs baseline: 1.0564x; 1.0564x over previous
//
#include <hip/hip_runtime.h>
#include <math.h>

// Problem constants
#define B_N 65536
#define G_N 6
#define IN_N 512
#define F_N 256
#define O_N 18

// Sort constants
#define NB 256     // histogram blocks (B_N / 256)
#define CHUNK 256

// Fused kernel tiling: 32 sorted rows per block, full N=256, 8 waves.
// TBM=32 keeps LDS at ~34KB -> 3-4 blocks/CU resident (vs 2 at TBM=64).
#define TBM 32
#define MAXT (B_N / TBM + G_N)   // 2054

typedef __bf16 bf16x8 __attribute__((ext_vector_type(8)));
typedef float f32x4 __attribute__((ext_vector_type(4)));

// ---- workspace layout (bytes) ----
#define WS_BC     0
#define WS_BOFF   8192
#define WS_NTILES 16448
#define WS_DESC   16512                         // 2054*12 = 24648 bytes, fits < 49024
#define WS_W1F    65536                         // 6 * 256KB = 1572864
#define WS_W2F    (WS_W1F + 1572864)            // 128KB
#define WS_WQT    (WS_W2F + 131072)             // 6*18*256*4 = 110592
#define WS_PERM   4194304

__device__ __forceinline__ unsigned short f2bf(float f) {
    union { float f; unsigned u; } a; a.f = f;
    unsigned r = a.u + 0x7fffu + ((a.u >> 16) & 1u);
    return (unsigned short)(r >> 16);
}
__device__ __forceinline__ unsigned pack2(float a, float b) {
    return (unsigned)f2bf(a) | ((unsigned)f2bf(b) << 16);
}
__device__ __forceinline__ bf16x8 asbf(uint4 u) {
    union { uint4 u; bf16x8 b; } c; c.u = u; return c.b;
}

// ---------- sort: histogram ----------
__global__ void k_hist(const int* __restrict__ idx, int* __restrict__ bc) {
    __shared__ int cnt[G_N];
    int t = threadIdx.x;
    if (t < G_N) cnt[t] = 0;
    __syncthreads();
    int e = blockIdx.x * CHUNK + t;
    atomicAdd(&cnt[idx[e]], 1);
    __syncthreads();
    if (t < G_N) bc[blockIdx.x * G_N + t] = cnt[t];
}

// ---------- sort: prefix + tile descriptors (single block, parallel scan) ----------
__global__ void k_prefix(const int* __restrict__ bc, int* __restrict__ boff,
                         int* __restrict__ ntiles, int* __restrict__ desc) {
    __shared__ int sbc[NB * G_N];   // 6 KB
    __shared__ int tot[G_N], st[G_N];
    __shared__ int tstart[G_N + 1];
    int t = threadIdx.x;
    for (int i = t; i < NB * G_N; i += 256) sbc[i] = bc[i];
    __syncthreads();
    int w = t >> 6, l = t & 63;
    for (int g = w; g < G_N; g += 4) {
        int v[4]; int s = 0;
#pragma unroll
        for (int j = 0; j < 4; j++) { v[j] = sbc[(l * 4 + j) * G_N + g]; s += v[j]; }
        int inc = s;
#pragma unroll
        for (int o = 1; o < 64; o <<= 1) { int x = __shfl_up(inc, o, 64); if (l >= o) inc += x; }
        int run = inc - s;   // exclusive prefix
        if (l == 63) tot[g] = inc;
#pragma unroll
        for (int j = 0; j < 4; j++) { sbc[(l * 4 + j) * G_N + g] = run; run += v[j]; }
    }
    __syncthreads();
    if (t == 0) {
        int acc = 0;
        for (int g = 0; g < G_N; g++) { st[g] = acc; acc += tot[g]; }
        int nt = 0;
        for (int g = 0; g < G_N; g++) { tstart[g] = nt; nt += (tot[g] + TBM - 1) / TBM; }
        tstart[G_N] = nt;
        *ntiles = nt;
    }
    __syncthreads();
    for (int i = t; i < NB * G_N; i += 256) boff[i] = sbc[i] + st[i % G_N];
    int nt = tstart[G_N];
    for (int i = t; i < MAXT; i += 256) {
        int gd = 0, r0 = 0, nr = 0;
        if (i < nt) {
            int g = 0;
            while (g < G_N - 1 && i >= tstart[g + 1]) g++;
            int k = i - tstart[g];
            r0 = st[g] + k * TBM;
            int rem = tot[g] - k * TBM;
            nr = rem < TBM ? rem : TBM;
            gd = g;
        }
        desc[i * 3 + 0] = gd; desc[i * 3 + 1] = r0; desc[i * 3 + 2] = nr;
    }
}

// ---------- sort: stable scatter ----------
__global__ void k_scatter(const int* __restrict__ idx, const int* __restrict__ boff,
                          int* __restrict__ perm) {
    __shared__ int wcnt[4][G_N];
    __shared__ int base[G_N];
    int t = threadIdx.x, w = t >> 6, l = t & 63;
    int e = blockIdx.x * CHUNK + t;
    int g = idx[e];
    int rank = 0;
    for (int gg = 0; gg < G_N; gg++) {
        unsigned long long m = __ballot(g == gg);
        if (g == gg) rank = __popcll(m & ((1ull << l) - 1ull));
        if (l == 0) wcnt[w][gg] = __popcll(m);
    }
    if (t < G_N) base[t] = boff[blockIdx.x * G_N + t];
    __syncthreads();
    int off = base[g] + rank;
    for (int ww = 0; ww < w; ww++) off += wcnt[ww][g];
    perm[off] = e;
}

// ---------- fused weight prep ----------
// z<6: pack W1[game z] ([512][256] f32 -> fragment-major bf16, kfTot=16)
// z==6, kf<8: pack W2 (kfTot=8)
// z==6, kf>=8: transpose Wq [G][256][18] -> WqT [G][18][256]
// dst pack layout: [w(8)][kf][frag(2)][lane(64)][8 shorts]; lane l holds
// n = w*32 + frag*16 + (l&15), k = kf*32 + (l>>4)*8 + j.
__global__ void k_pack_all(const float* __restrict__ W1, const float* __restrict__ W2,
                           const float* __restrict__ Wq,
                           unsigned short* __restrict__ W1f, unsigned short* __restrict__ W2f,
                           float* __restrict__ WqT) {
    int kf = blockIdx.x, w = blockIdx.y, z = blockIdx.z;
    if (z == 6 && kf >= 8) {
        // WqT: 64 blocks * 128 threads cover 6*18*256 = 27648 elements
        int tid = ((kf - 8) * 8 + w) * 128 + threadIdx.x;   // 0..8191
        for (int e = tid; e < G_N * O_N * F_N; e += 8192) {
            int f = e & (F_N - 1);
            int go = e >> 8;            // g*O_N + o
            int g = go / O_N, o = go - g * O_N;
            WqT[e] = Wq[((long)g * F_N + f) * O_N + o];
        }
        return;
    }
    const float* src;
    unsigned short* dst;
    int kfTot;
    if (z < 6) { src = W1 + (long)z * IN_N * F_N; dst = W1f + (long)z * IN_N * F_N; kfTot = 16; }
    else       { src = W2; dst = W2f; kfTot = 8; }
    int f = threadIdx.x >> 6, l = threadIdx.x & 63;
    int lrow = l & 15, q = l >> 4;
    int n = w * 32 + f * 16 + lrow;
    int k0 = kf * 32 + q * 8;
    const float* s = src + (long)k0 * F_N + n;
    unsigned o[4];
#pragma unroll
    for (int j = 0; j < 4; j++)
        o[j] = pack2(s[(2 * j) * F_N], s[(2 * j + 1) * F_N]);
    unsigned short* d = dst + ((((long)w * kfTot + kf) * 2 + f) * 64 + l) * 8;
    uint4 v = { o[0], o[1], o[2], o[3] };
    *(uint4*)d = v;
}

// ---------- fused: expert GEMM -> sigmoid -> shared GEMM -> relu -> Q-head dot -> tanh ----------
// Block: 32 sorted positions (one game tile), full N=256. 8 waves, wave w owns
// n-slice [w*32, w*32+32). A staged ONCE to LDS (bf16, XOR-swizzled). B frags
// are fragment-major packed -> every K-loop load is a coalesced 1KB wave-load.
// LDS ~34KB -> 4 blocks/CU (vs 2 at TBM=64): the kernel was latency-bound
// (MfmaUtil 10%, HBM 10%, Occ 37%), so resident-block overlap is the lever.
// Reference quirk: Q-head uses idx[pos]/action[pos] (original-order arrays at
// the sorted position); output lands at position pos.
__global__ __launch_bounds__(512, 6) void k_fused(
    const float* __restrict__ state, const char* __restrict__ w1f,
    const char* __restrict__ w2f, const float* __restrict__ wqt,
    const float* __restrict__ b1, const float* __restrict__ b2,
    const float* __restrict__ bqv,
    const int* __restrict__ action, const int* __restrict__ idx,
    const int* __restrict__ perm, const int* __restrict__ desc,
    float* __restrict__ out) {
    int td = blockIdx.x;
    int g = desc[td * 3 + 0], row0 = desc[td * 3 + 1], nr = desc[td * 3 + 2];
    if (nr == 0) return;

    __shared__ __align__(16) unsigned short smA[TBM * 512];   // 32 KB; front 16 KB reused as H1
    __shared__ float partial[TBM][9];
    __shared__ int gq[TBM], actv[TBM];
    unsigned short* smH = smA;

    int t = threadIdx.x, w = t >> 6, l = t & 63;
    int lrow = l & 15, q = l >> 4;
    int x0 = lrow & 7;

    // ---- issue first B loads early (independent of LDS) ----
    const char* B1 = w1f + (((long)g * 8 + w) << 15) + l * 16;
    uint4 nb0 = *(const uint4*)(B1);
    uint4 nb1 = *(const uint4*)(B1 + 1024);

    if (t < TBM) {
        int pos = row0 + t; if (pos > B_N - 1) pos = B_N - 1;
        gq[t] = idx[pos];        // ORIGINAL-order idx at sorted position
        actv[t] = action[pos];   // ORIGINAL-order action at sorted position
    }

    // ---- stage A once: 16 threads/row, each 8x(float4 load + cvt + ds_write_b64) ----
    {
        int m = t >> 4, s = t & 15;
        int pr = row0 + m; if (pr > B_N - 1) pr = B_N - 1;
        const float* src = state + (long)perm[pr] * IN_N + s * 4;
        int cb = s >> 1, h = s & 1, mx = m & 7;
        char* rowbase = (char*)smA + m * 1024 + h * 8;
#pragma unroll
        for (int j = 0; j < 8; j++) {
            float4 v = *(const float4*)(src + j * 64);
            uint2 p = { pack2(v.x, v.y), pack2(v.z, v.w) };
            int c = (cb + j * 8) ^ mx;
            *(uint2*)(rowbase + c * 16) = p;
        }
    }
    __syncthreads();

    // ---- phase 1: H1 = sigmoid(A @ W1[g] + b1[g]), K=512, no barriers in loop ----
    const char* ar[2];
#pragma unroll
    for (int i = 0; i < 2; i++) ar[i] = (const char*)smA + (i * 16 + lrow) * 1024;

    f32x4 acc[2][2];
#pragma unroll
    for (int i = 0; i < 2; i++)
#pragma unroll
        for (int j = 0; j < 2; j++) acc[i][j] = (f32x4){0.f, 0.f, 0.f, 0.f};

#pragma unroll
    for (int kf = 0; kf < 16; kf++) {
        uint4 cb0 = nb0, cb1 = nb1;
        if (kf < 15) {
            nb0 = *(const uint4*)(B1 + (kf + 1) * 2048);
            nb1 = *(const uint4*)(B1 + (kf + 1) * 2048 + 1024);
        }
        int c = ((kf * 4 + q) ^ x0) * 16;
        bf16x8 af[2];
#pragma unroll
        for (int i = 0; i < 2; i++) af[i] = *(const bf16x8*)(ar[i] + c);
        bf16x8 b0 = asbf(cb0), b1v = asbf(cb1);
#pragma unroll
        for (int i = 0; i < 2; i++) {
            acc[i][0] = __builtin_amdgcn_mfma_f32_16x16x32_bf16(af[i], b0, acc[i][0], 0, 0, 0);
            acc[i][1] = __builtin_amdgcn_mfma_f32_16x16x32_bf16(af[i], b1v, acc[i][1], 0, 0, 0);
        }
    }
    __syncthreads();   // all A reads done; smA front 16KB becomes H1

    // ---- epilogue 1: sigmoid -> bf16 -> swizzled LDS H1[32][256] ----
    {
        int col0 = w * 32 + lrow;
#pragma unroll
        for (int j = 0; j < 2; j++) {
            int col = col0 + j * 16;
            float bias = b1[g * F_N + col];
            int cc = col >> 3, cb2 = (col & 7) * 2;
#pragma unroll
            for (int i = 0; i < 2; i++)
#pragma unroll
                for (int r = 0; r < 4; r++) {
                    int row = i * 16 + q * 4 + r;
                    float v = acc[i][j][r] + bias;
                    float sg = 1.0f / (1.0f + __expf(-v));
                    int c = cc ^ (row & 7);
                    *(unsigned short*)((char*)smH + row * 512 + c * 16 + cb2) = f2bf(sg);
                }
        }
    }
    __syncthreads();

    // ---- phase 2: HF = relu(H1 @ W2 + b2), K=256, no barriers in loop ----
    const char* B2 = w2f + ((long)w << 14) + l * 16;
    const char* hr[2];
#pragma unroll
    for (int i = 0; i < 2; i++) hr[i] = (const char*)smH + (i * 16 + lrow) * 512;

    f32x4 acc2[2][2];
#pragma unroll
    for (int i = 0; i < 2; i++)
#pragma unroll
        for (int j = 0; j < 2; j++) acc2[i][j] = (f32x4){0.f, 0.f, 0.f, 0.f};

    uint4 m0 = *(const uint4*)(B2);
    uint4 m1 = *(const uint4*)(B2 + 1024);
#pragma unroll
    for (int kf = 0; kf < 8; kf++) {
        uint4 c0 = m0, c1 = m1;
        if (kf < 7) {
            m0 = *(const uint4*)(B2 + (kf + 1) * 2048);
            m1 = *(const uint4*)(B2 + (kf + 1) * 2048 + 1024);
        }
        int c = ((kf * 4 + q) ^ x0) * 16;
        bf16x8 af[2];
#pragma unroll
        for (int i = 0; i < 2; i++) af[i] = *(const bf16x8*)(hr[i] + c);
        bf16x8 b0 = asbf(c0), b1v = asbf(c1);
#pragma unroll
        for (int i = 0; i < 2; i++) {
            acc2[i][0] = __builtin_amdgcn_mfma_f32_16x16x32_bf16(af[i], b0, acc2[i][0], 0, 0, 0);
            acc2[i][1] = __builtin_amdgcn_mfma_f32_16x16x32_bf16(af[i], b1v, acc2[i][1], 0, 0, 0);
        }
    }

    // ---- final: per-row dot with WqT[idx[pos]][action[pos]][:], wave-partial reduce ----
    {
        int col0 = w * 32 + lrow;
        float bias0 = b2[col0], bias1 = b2[col0 + 16];
#pragma unroll
        for (int i = 0; i < 2; i++)
#pragma unroll
            for (int r = 0; r < 4; r++) {
                int row = i * 16 + q * 4 + r;
                const float* wp = wqt + ((long)gq[row] * O_N + actv[row]) * F_N;
                float v0 = fmaxf(acc2[i][0][r] + bias0, 0.0f);
                float v1 = fmaxf(acc2[i][1][r] + bias1, 0.0f);
                float s = v0 * wp[col0] + v1 * wp[col0 + 16];
                s += __shfl_xor(s, 1, 64);
                s += __shfl_xor(s, 2, 64);
                s += __shfl_xor(s, 4, 64);
                s += __shfl_xor(s, 8, 64);
                if (lrow == 0) partial[row][w] = s;
            }
    }
    __syncthreads();
    if (t < TBM && t < nr) {
        float s = 0.f;
#pragma unroll
        for (int ww = 0; ww < 8; ww++) s += partial[t][ww];
        out[row0 + t] = tanhf(s + bqv[gq[t] * O_N + actv[t]]);
    }
}

extern "C" void kernel_launch(void* const* d_in, const int* in_sizes, int n_in,
                              void* d_out, int out_size, void* d_ws, size_t ws_size,
                              hipStream_t stream) {
    const float* state  = (const float*)d_in[0];
    const int*   action = (const int*)d_in[1];
    const int*   idx    = (const int*)d_in[2];
    const float* W1     = (const float*)d_in[3];
    const float* b1     = (const float*)d_in[4];
    const float* W2     = (const float*)d_in[5];
    const float* b2     = (const float*)d_in[6];
    const float* Wq     = (const float*)d_in[7];
    const float* bq     = (const float*)d_in[8];
    float* out = (float*)d_out;

    char* ws = (char*)d_ws;
    int* bc      = (int*)(ws + WS_BC);
    int* boff    = (int*)(ws + WS_BOFF);
    int* ntiles  = (int*)(ws + WS_NTILES);
    int* desc    = (int*)(ws + WS_DESC);
    unsigned short* W1f = (unsigned short*)(ws + WS_W1F);
    unsigned short* W2f = (unsigned short*)(ws + WS_W2F);
    float* WqT   = (float*)(ws + WS_WQT);
    int* perm    = (int*)(ws + WS_PERM);

    k_hist<<<NB, CHUNK, 0, stream>>>(idx, bc);
    k_prefix<<<1, 256, 0, stream>>>(bc, boff, ntiles, desc);
    k_scatter<<<NB, CHUNK, 0, stream>>>(idx, boff, perm);
    k_pack_all<<<dim3(16, 8, 7), 128, 0, stream>>>(W1, W2, Wq, W1f, W2f, WqT);
    k_fused<<<MAXT, 512, 0, stream>>>(state, (const char*)W1f, (const char*)W2f, WqT,
                                      b1, b2, bq, action, idx, perm, desc, out);
}